// Round 11
// baseline (139.728 us; speedup 1.0000x reference)
//
#include <hip/hip_runtime.h>
#include <hip/hip_bf16.h>
#include <cstdint>
#include <cstddef>

// ---------------------------------------------------------------------------
// ThreeLayerFCModel: out = relu(relu(relu(x@w0^T+b0)@(w1*m1)^T+b1)@(w2*m2)^T+b2)
// B=16384, dims 1024. Round 11: R3 schedule (proven best) with MFMA shape
// switched 16x16x32 -> 32x32x16 (half the instructions, 17% less matrix-pipe
// time, same LDS bytes / registers). Inline mask-dtype detection in prep.
// ---------------------------------------------------------------------------

typedef __bf16 bf16x8 __attribute__((ext_vector_type(8)));
typedef float  f32x16 __attribute__((ext_vector_type(16)));

#define AS1 __attribute__((address_space(1)))
#define AS3 __attribute__((address_space(3)))

__device__ __forceinline__ void gload_lds16(const void* g, void* l) {
    __builtin_amdgcn_global_load_lds((const AS1 void*)g, (AS3 void*)l, 16, 0, 0);
}

// ---------------- fused prep: cvt x->bf16 + 3x (w*mask)->bf16 ---------------
// Mask dtype (uint8 / int32 / f32) detected per-block from m1's first 1KB.
__device__ __forceinline__ void prep_body(const float* __restrict__ w,
                                          const void* __restrict__ mask, int mode,
                                          __bf16* __restrict__ out, long i) {
    float4 a = *reinterpret_cast<const float4*>(w + i);
    float4 b = *reinterpret_cast<const float4*>(w + i + 4);
    float v[8] = {a.x, a.y, a.z, a.w, b.x, b.y, b.z, b.w};
    if (mask) {
        if (mode == 1) {
            const unsigned char* mp = (const unsigned char*)mask;
            #pragma unroll
            for (int j = 0; j < 8; ++j) v[j] = mp[i + j] ? v[j] : 0.f;
        } else if (mode == 0) {
            const int* mp = (const int*)mask;
            #pragma unroll
            for (int j = 0; j < 8; ++j) v[j] = mp[i + j] ? v[j] : 0.f;
        } else {
            const float* mp = (const float*)mask;
            #pragma unroll
            for (int j = 0; j < 8; ++j) v[j] = (mp[i + j] != 0.f) ? v[j] : 0.f;
        }
    }
    bf16x8 o;
    #pragma unroll
    for (int j = 0; j < 8; ++j) o[j] = (__bf16)v[j];
    *reinterpret_cast<bf16x8*>(out + i) = o;
}

__global__ void prep_all(const float* __restrict__ x, __bf16* __restrict__ xb,
                         const float* __restrict__ w0, const float* __restrict__ w1,
                         const float* __restrict__ w2,
                         const void* __restrict__ m1, const void* __restrict__ m2,
                         __bf16* __restrict__ w0b, __bf16* __restrict__ w1b,
                         __bf16* __restrict__ w2b) {
    const int bid = blockIdx.x;
    const int t   = threadIdx.x;
    if (bid < 8192) {  // x -> bf16 (16M elems)
        long i = ((long)bid * blockDim.x + t) * 8;
        float4 a = *reinterpret_cast<const float4*>(x + i);
        float4 b = *reinterpret_cast<const float4*>(x + i + 4);
        bf16x8 o;
        o[0] = (__bf16)a.x; o[1] = (__bf16)a.y; o[2] = (__bf16)a.z; o[3] = (__bf16)a.w;
        o[4] = (__bf16)b.x; o[5] = (__bf16)b.y; o[6] = (__bf16)b.z; o[7] = (__bf16)b.w;
        *reinterpret_cast<bf16x8*>(xb + i) = o;
    } else {
        // inline mask-dtype detection (same bytes for m1/m2; L2-cached)
        __shared__ int smode;
        if (t < 64) {
            const unsigned char* mm = (const unsigned char*)m1;
            int or1 = 0, or3 = 0;
            for (int e = t; e < 256; e += 64) { or1 |= mm[e * 4 + 1]; or3 |= mm[e * 4 + 3]; }
            unsigned long long b1 = __ballot(or1 != 0);
            unsigned long long b3 = __ballot(or3 != 0);
            if (t == 0) smode = b1 ? 1 : (b3 ? 2 : 0);
        }
        __syncthreads();
        const int mode = smode;
        const int q = bid - 8192, wi = q >> 9, sub = q & 511;
        long i = ((long)sub * blockDim.x + t) * 8;
        if (wi == 0)      prep_body(w0, nullptr, mode, w0b, i);
        else if (wi == 1) prep_body(w1, m1,      mode, w1b, i);
        else              prep_body(w2, m2,      mode, w2b, i);
    }
}

// ---------------------------------------------------------------------------
// 256x256-tile GEMM: C = relu(A[16384,1024] * W[1024,1024]^T + bias)
// 512 thr = 8 waves (2 row x 4 col), per-wave 128x64 out via 4x2 tiles of
// 32x32, mfma_f32_32x32x16_bf16, BK=64 (4 k-chunks of 16), 16 K-tiles.
// LDS 128 KiB: A/B each [2 dbuf][256 rows][64 k] bf16, XOR-swizzled (T2).
// Schedule (R3): ph0 read all B (8) + A mt0,mt1 (8), MFMA mt0; ph1 stage
// B(t+2)h0, read mt2, MFMA mt1; ph2 stage B(t+2)h1, read mt3, MFMA mt2;
// ph3 stage A(t+2), MFMA mt3, boundary vmcnt(8). LGKM0+BAR each phase end.
// A-frag: lane row=l&31 (+mt*32+wr*128), k=(l>>5)*8+kc*16. B symmetric.
// C/D: col=l&31, row=(reg&3)+8*(reg>>2)+4*(l>>5)  [m74/m101 verified].
// ---------------------------------------------------------------------------
__device__ __forceinline__ f32x16 mfma32(bf16x8 a, bf16x8 b, f32x16 c) {
    return __builtin_amdgcn_mfma_f32_32x32x16_bf16(a, b, c, 0, 0, 0);
}

#define MFMAG(MT, A)                                                        \
    __builtin_amdgcn_s_setprio(1);                                          \
    _Pragma("unroll")                                                       \
    for (int kc = 0; kc < 4; ++kc) {                                        \
        acc[MT][0] = mfma32(A[kc], b[0][kc], acc[MT][0]);                   \
        acc[MT][1] = mfma32(A[kc], b[1][kc], acc[MT][1]);                   \
    }                                                                       \
    __builtin_amdgcn_s_setprio(0);

#define BAR()   __builtin_amdgcn_s_barrier(); __builtin_amdgcn_sched_barrier(0)
#define LGKM0() asm volatile("s_waitcnt lgkmcnt(0)" ::: "memory")
#define VM8()   asm volatile("s_waitcnt vmcnt(8)" ::: "memory")
#define VM0()   asm volatile("s_waitcnt vmcnt(0)" ::: "memory")

template<bool F32OUT>
__global__ __launch_bounds__(512, 2) void gemm8p(
    const __bf16* __restrict__ A, const __bf16* __restrict__ W,
    const float* __restrict__ bias,
    __bf16* __restrict__ outb, float* __restrict__ outf) {
    constexpr int NT = 16;  // K/64
    extern __shared__ char smem[];  // A: [0,64K), B: [64K,128K)

    const int t    = threadIdx.x;
    const int l    = t & 63, l31 = l & 31, lhi5 = l >> 5;
    const int w    = t >> 6, wr = w >> 2, wc = w & 3;

    // T1: bijective XCD swizzle (256 blocks, 8 XCDs)
    const int bid = blockIdx.x;
    const int swz = (bid & 7) * 32 + (bid >> 3);
    const int bx = swz & 3, by = swz >> 2;
    const int brow = by * 256, bcol = bx * 256;

    // staging consts: row = t>>3, in-row 16B block (t&7) XOR'd by row&7 (T2).
    const int srow = t >> 3;
    const int scol = (((t & 7) ^ ((t >> 3) & 7)) << 4) >> 1;
    const __bf16* gA = A + (size_t)(brow + srow) * 1024 + scol;
    const __bf16* gW = W + (size_t)(bcol + srow) * 1024 + scol;
    const int woff = (t & 448) * 16;  // wave*1024 (wave-uniform)

    char* const ldsA = smem;
    char* const ldsB = smem + 65536;

    auto stageAfull = [&](int d, int k0) {  // 4 ops: 256 rows x 64k
        const __bf16* g = gA + k0;
        char* p = ldsA + d * 32768 + woff;
        gload_lds16(g,          p);
        gload_lds16(g + 65536,  p + 8192);
        gload_lds16(g + 131072, p + 16384);
        gload_lds16(g + 196608, p + 24576);
    };
    auto stageBh = [&](int d, int h, int k0) {  // 2 ops: 128 rows x 64k
        const __bf16* g = gW + (size_t)h * 131072 + k0;
        char* p = ldsB + d * 32768 + h * 16384 + woff;
        gload_lds16(g, p);
        gload_lds16(g + 65536, p + 8192);
    };

    // fragment-read consts (T2 swizzled). Row stride 128B.
    // A row for tile mt: wr*128 + mt*32 + l31; k-byte = kc*32 + lhi5*16.
    const int xorm = (l & 7) << 4;  // row&7 == l&7 (row offsets are mult of 32)
    int koff[4];
    #pragma unroll
    for (int kc = 0; kc < 4; ++kc) koff[kc] = (kc * 32 + lhi5 * 16) ^ xorm;
    char* const aBase = ldsA + (wr * 128 + l31) * 128;
    char* const bBase = ldsB + (wc * 64 + l31) * 128;

    f32x16 acc[4][2] = {};

    // prologue: stage tiles 0,1 (16 ops); VM8 drains tile0's 8
    stageAfull(0, 0);  stageBh(0, 0, 0);  stageBh(0, 1, 0);
    stageAfull(1, 64); stageBh(1, 0, 64); stageBh(1, 1, 64);
    VM8(); BAR();

    #pragma unroll 2
    for (int tt = 0; tt < NT; ++tt) {
        const int d  = tt & 1;
        const int k2 = (tt + 2) * 64;
        char* const aB = aBase + d * 32768;
        char* const bB = bBase + d * 32768;
        const bool st = (tt + 2 < NT);

        // ---- ph0: read all B frags + A mt0,mt1; MFMA mt0 ----
        bf16x8 b[2][4], a[4], c[4];
        #pragma unroll
        for (int kc = 0; kc < 4; ++kc) {
            b[0][kc] = *(const bf16x8*)(bB + 0 * 4096 + koff[kc]);
            b[1][kc] = *(const bf16x8*)(bB + 1 * 4096 + koff[kc]);
        }
        #pragma unroll
        for (int kc = 0; kc < 4; ++kc) {
            a[kc] = *(const bf16x8*)(aB + 0 * 4096 + koff[kc]);
            c[kc] = *(const bf16x8*)(aB + 1 * 4096 + koff[kc]);
        }
        MFMAG(0, a);
        LGKM0(); BAR();

        // ---- ph1: stage B(t+2)h0; read mt2; MFMA mt1 ----
        if (st) stageBh(d, 0, k2);
        #pragma unroll
        for (int kc = 0; kc < 4; ++kc)
            a[kc] = *(const bf16x8*)(aB + 2 * 4096 + koff[kc]);
        MFMAG(1, c);
        LGKM0(); BAR();

        // ---- ph2: stage B(t+2)h1; read mt3; MFMA mt2 ----
        if (st) stageBh(d, 1, k2);
        #pragma unroll
        for (int kc = 0; kc < 4; ++kc)
            c[kc] = *(const bf16x8*)(aB + 3 * 4096 + koff[kc]);
        MFMAG(2, a);
        LGKM0(); BAR();

        // ---- ph3: stage A(t+2); MFMA mt3; counted boundary wait ----
        if (st) stageAfull(d, k2);
        MFMAG(3, c);
        if (tt <= NT - 3)      { VM8(); BAR(); }
        else if (tt == NT - 2) { VM0(); BAR(); }
    }

    // ---- epilogue: C/D col = l31, row = (r&3)+8*(r>>2)+4*lhi5 (r=0..15) ----
    if constexpr (F32OUT) {
        // restage through LDS in two 128-row chunks -> coalesced dwordx4
        char* const cl = smem;
        #pragma unroll
        for (int chunk = 0; chunk < 2; ++chunk) {
            __syncthreads();
            if (wr == chunk) {
                #pragma unroll
                for (int nt = 0; nt < 2; ++nt) {
                    const int col = wc * 64 + nt * 32 + l31;
                    const int colb = col * 4;
                    const float bv = bias[bcol + col];
                    #pragma unroll
                    for (int mt = 0; mt < 4; ++mt) {
                        #pragma unroll
                        for (int r = 0; r < 16; ++r) {
                            const int row = mt * 32 + (r & 3) + 8 * (r >> 2) + 4 * lhi5;
                            float v = acc[mt][nt][r] + bv;
                            v = v > 0.f ? v : 0.f;
                            *(float*)(cl + row * 1024 + (colb ^ ((row & 12) << 4))) = v;
                        }
                    }
                }
            }
            __syncthreads();
            #pragma unroll
            for (int rd = 0; rd < 16; ++rd) {
                const int off = rd * 8192 + t * 16;
                const int row = off >> 10;
                const int cb  = (off & 1023) ^ ((row & 12) << 4);
                float4 v = *(const float4*)(cl + off);
                *(float4*)((char*)outf +
                           ((size_t)(brow + chunk * 128 + row) * 1024 + bcol) * 4 + cb) = v;
            }
        }
    } else {
        // restage C tile (256x256 bf16 = 128K) in LDS, then coalesced stores
        __syncthreads();
        char* const cl = smem;
        #pragma unroll
        for (int nt = 0; nt < 2; ++nt) {
            const int col = wc * 64 + nt * 32 + l31;
            const int colb = col * 2;
            const float bv = bias[bcol + col];
            #pragma unroll
            for (int mt = 0; mt < 4; ++mt) {
                #pragma unroll
                for (int r = 0; r < 16; ++r) {
                    const int row = wr * 128 + mt * 32 + (r & 3) + 8 * (r >> 2) + 4 * lhi5;
                    float v = acc[mt][nt][r] + bv;
                    v = v > 0.f ? v : 0.f;
                    *(__bf16*)(cl + row * 512 + (colb ^ ((row & 12) << 3))) = (__bf16)v;
                }
            }
        }
        __syncthreads();
        #pragma unroll
        for (int rd = 0; rd < 16; ++rd) {
            const int off = rd * 8192 + t * 16;
            const int row = off >> 9;
            const int cb  = (off & 511) ^ ((row & 12) << 3);
            bf16x8 v = *(const bf16x8*)(cl + off);
            *(bf16x8*)((char*)outb + ((size_t)(brow + row) * 1024 + bcol) * 2 + cb) = v;
        }
    }
}

// ---------------------------------------------------------------------------
extern "C" void kernel_launch(void* const* d_in, const int* in_sizes, int n_in,
                              void* d_out, int out_size, void* d_ws, size_t ws_size,
                              hipStream_t stream) {
    const float* x  = (const float*)d_in[0];
    const float* w0 = (const float*)d_in[1];
    const float* b0 = (const float*)d_in[2];
    const float* w1 = (const float*)d_in[3];
    const float* b1 = (const float*)d_in[4];
    const void*  m1 = d_in[5];
    const float* w2 = (const float*)d_in[6];
    const float* b2 = (const float*)d_in[7];
    const void*  m2 = d_in[8];
    float* out = (float*)d_out;

    char* ws = (char*)d_ws;
    __bf16* xb  = (__bf16*)(ws);                             // 32 MiB (x, later h2)
    __bf16* h1  = (__bf16*)(ws + (size_t)32 * 1024 * 1024);  // 32 MiB
    __bf16* w0b = (__bf16*)(ws + (size_t)64 * 1024 * 1024);
    __bf16* w1b = w0b + 1024 * 1024;
    __bf16* w2b = w1b + 1024 * 1024;

    hipFuncSetAttribute((const void*)gemm8p<false>,
                        hipFuncAttributeMaxDynamicSharedMemorySize, 131072);
    hipFuncSetAttribute((const void*)gemm8p<true>,
                        hipFuncAttributeMaxDynamicSharedMemorySize, 131072);

    prep_all<<<9728, 256, 0, stream>>>(x, xb, w0, w1, w2, m1, m2,
                                       w0b, w1b, w2b);

    gemm8p<false><<<256, 512, 131072, stream>>>(xb, w0b, b0, h1, nullptr);
    gemm8p<false><<<256, 512, 131072, stream>>>(h1, w1b, b1, xb, nullptr);  // h2 -> xb
    gemm8p<true ><<<256, 512, 131072, stream>>>(xb, w2b, b2, nullptr, out);
}